// Round 2
// baseline (21.406 us; speedup 1.0000x reference)
//
#include <hip/hip_runtime.h>

// out[b][s][d] = W[d][s] + bias[d], b<4, s<4096, d<1024
// W: [1024][8192] fp32 row-major; out: [4][4096][1024] fp32.
// Memory-bound transpose-broadcast. LDS 64x64 tile (+1 pad) for the
// transpose; coalesced float4 on both sides; each tile value stored to
// all 4 batches from registers. Streaming traffic (W in, out) is
// nontemporal to bypass L2 allocation (no reuse on either side).

constexpr int S = 4096;
constexpr int D = 1024;
constexpr int MAXLEN = 8192;
constexpr int BATCH = 4;
constexpr int TS = 64;   // tile extent along s
constexpr int TD = 64;   // tile extent along d
constexpr int PAD = 1;   // LDS row stride 65 floats -> 2 lanes/bank (free)

typedef float v4f __attribute__((ext_vector_type(4)));

__global__ __launch_bounds__(256)
void pos_emb_kernel(const float* __restrict__ W,
                    const float* __restrict__ bias,
                    float* __restrict__ out)
{
    __shared__ float tile[TD][TS + PAD];

    constexpr int nTileS = S / TS;             // 64
    const int ts = blockIdx.x % nTileS;
    const int td = blockIdx.x / nTileS;
    const int s0 = ts * TS;
    const int d0 = td * TD;
    const int tid = threadIdx.x;

    // ---- Load phase: lanes along s (coalesced float4 from W rows) ----
    {
        const int c4 = tid & 15;   // which float4 within the s-row (16 per row)
        const int r  = tid >> 4;   // d-row base (0..15), 4 passes of 16 rows
        #pragma unroll
        for (int i = 0; i < 4; ++i) {
            const int dl = r + i * 16;
            const v4f v = __builtin_nontemporal_load(
                reinterpret_cast<const v4f*>(
                    &W[(size_t)(d0 + dl) * MAXLEN + s0 + c4 * 4]));
            tile[dl][c4 * 4 + 0] = v.x;
            tile[dl][c4 * 4 + 1] = v.y;
            tile[dl][c4 * 4 + 2] = v.z;
            tile[dl][c4 * 4 + 3] = v.w;
        }
    }
    __syncthreads();

    // ---- Store phase: lanes along d (coalesced float4 to out rows) ----
    {
        const int cd = tid & 15;   // which float4 along d (16 per row)
        const int rs = tid >> 4;   // s-row base (0..15), 4 passes of 16 rows
        const float4 bv = *reinterpret_cast<const float4*>(&bias[d0 + cd * 4]);
        #pragma unroll
        for (int i = 0; i < 4; ++i) {
            const int sl = rs + i * 16;
            v4f v;
            v.x = tile[cd * 4 + 0][sl] + bv.x;
            v.y = tile[cd * 4 + 1][sl] + bv.y;
            v.z = tile[cd * 4 + 2][sl] + bv.z;
            v.w = tile[cd * 4 + 3][sl] + bv.w;
            const size_t base = (size_t)(s0 + sl) * D + d0 + cd * 4;
            #pragma unroll
            for (int b = 0; b < BATCH; ++b) {
                __builtin_nontemporal_store(
                    v, reinterpret_cast<v4f*>(&out[base + (size_t)b * S * D]));
            }
        }
    }
}

extern "C" void kernel_launch(void* const* d_in, const int* in_sizes, int n_in,
                              void* d_out, int out_size, void* d_ws, size_t ws_size,
                              hipStream_t stream) {
    // setup_inputs order: x (unused), W, b
    const float* W    = (const float*)d_in[1];
    const float* bias = (const float*)d_in[2];
    float* out        = (float*)d_out;

    const int grid = (S / TS) * (D / TD);   // 1024 blocks, 256 threads
    pos_emb_kernel<<<grid, 256, 0, stream>>>(W, bias, out);
}

// Round 3
// 17.952 us; speedup vs baseline: 1.1924x; 1.1924x over previous
//
#include <hip/hip_runtime.h>

// out[b][s][d] = W[d][s] + bias[d], b<4, s<4096, d<1024
// W: [1024][8192] fp32 row-major; out: [4][4096][1024] fp32.
// Memory-bound transpose-broadcast. LDS 64x32 (+1 pad) transpose tile;
// coalesced float4 on both sides; batch replication from registers.
// TS=32 -> 2048 blocks = 8 blocks/CU = 32 waves/CU (full occupancy)
// so load-phase and store-phase blocks overlap on every CU.
// NT load/store reverted: measured -19% (R2).

constexpr int S = 4096;
constexpr int D = 1024;
constexpr int MAXLEN = 8192;
constexpr int BATCH = 4;
constexpr int TS = 32;   // tile extent along s
constexpr int TD = 64;   // tile extent along d
constexpr int PAD = 1;   // LDS row stride 33 floats -> 2 lanes/bank (free)

__global__ __launch_bounds__(256)
void pos_emb_kernel(const float* __restrict__ W,
                    const float* __restrict__ bias,
                    float* __restrict__ out)
{
    __shared__ float tile[TD][TS + PAD];

    constexpr int nTileS = S / TS;             // 128
    const int ts = blockIdx.x % nTileS;
    const int td = blockIdx.x / nTileS;
    const int s0 = ts * TS;
    const int d0 = td * TD;
    const int tid = threadIdx.x;

    // ---- Load phase: lanes along s (coalesced float4 from W rows) ----
    // 64 d-rows x 32 floats = 8 float4 per row; 256 threads -> 2 passes.
    {
        const int c4 = tid & 7;    // which float4 within the s-row (8 per row)
        const int r  = tid >> 3;   // d-row base (0..31), 2 passes of 32 rows
        #pragma unroll
        for (int i = 0; i < 2; ++i) {
            const int dl = r + i * 32;
            const float4 v = *reinterpret_cast<const float4*>(
                &W[(size_t)(d0 + dl) * MAXLEN + s0 + c4 * 4]);
            tile[dl][c4 * 4 + 0] = v.x;
            tile[dl][c4 * 4 + 1] = v.y;
            tile[dl][c4 * 4 + 2] = v.z;
            tile[dl][c4 * 4 + 3] = v.w;
        }
    }
    __syncthreads();

    // ---- Store phase: lanes along d (coalesced float4 to out rows) ----
    // 32 s-rows x 16 float4 along d; 256 threads -> 2 passes; x4 batches.
    {
        const int cd = tid & 15;   // which float4 along d (16 per row)
        const int rs = tid >> 4;   // s-row base (0..15), 2 passes of 16 rows
        const float4 bv = *reinterpret_cast<const float4*>(&bias[d0 + cd * 4]);
        #pragma unroll
        for (int i = 0; i < 2; ++i) {
            const int sl = rs + i * 16;
            float4 v;
            v.x = tile[cd * 4 + 0][sl] + bv.x;
            v.y = tile[cd * 4 + 1][sl] + bv.y;
            v.z = tile[cd * 4 + 2][sl] + bv.z;
            v.w = tile[cd * 4 + 3][sl] + bv.w;
            const size_t base = (size_t)(s0 + sl) * D + d0 + cd * 4;
            #pragma unroll
            for (int b = 0; b < BATCH; ++b) {
                *reinterpret_cast<float4*>(&out[base + (size_t)b * S * D]) = v;
            }
        }
    }
}

extern "C" void kernel_launch(void* const* d_in, const int* in_sizes, int n_in,
                              void* d_out, int out_size, void* d_ws, size_t ws_size,
                              hipStream_t stream) {
    // setup_inputs order: x (unused), W, b
    const float* W    = (const float*)d_in[1];
    const float* bias = (const float*)d_in[2];
    float* out        = (float*)d_out;

    const int grid = (S / TS) * (D / TD);   // 2048 blocks, 256 threads
    pos_emb_kernel<<<grid, 256, 0, stream>>>(W, bias, out);
}